// Round 8
// baseline (356.712 us; speedup 1.0000x reference)
//
#include <hip/hip_runtime.h>
#include <hip/hip_bf16.h>

// AdaptiveReLULayer: out[b,n,o] = leaky( sum_i x[b,n,i] * weight[idx[b],i,o] + bias[o], 0.2 )
// B=2048, N=256, IN=256, OUT=256, C=1024.  f32 I/O; bf16 MFMA, f32 accum.
//
// R10 vs R9 (294us; 7th variant in the 294-307 band): the invariant across
// all variants is load-queue DUTY CYCLE -- bursty loads + barrier convoys
// keep the HBM queue full ~50% of the time (3.3-3.6 TB/s), while the
// observed fillBufferAligned dispatch proves 6.5 TB/s at 10% occupancy for
// a fire-and-forget (store) stream.  R10 is the untested cell: BARRIER-FREE
// K-loop with collapse-proof prefetch:
//   * w half-panel (128 cols) -> 64KB bf16 B^T LDS once (reg-staged depth-2,
//     col-XOR swizzle); ONE s_barrier in the whole kernel.
//   * x: per-wave PRIVATE A-tiles via global_load_lds DMA (f32, linear LDS
//     dest + pre-swizzled global source), double-buffered, prefetch depth 2,
//     hand-counted s_waitcnt vmcnt(2).  In-flight depth lives in the vmcnt
//     counter, NOT in VGPRs -> the compiler cannot sink it (R5/R7 lesson).
//   * A private + B read-only => no barriers in the K-loop; waves free-run
//     and issue continuously.  f32->bf16 cvt at consume (4 pk2/k-step).
//   * LDS 80KB -> 2 blocks/CU; o-twin blocks adjacent in XCD swizzle so the
//     duplicated x read twin-hits L2 (watch FETCH for confirmation).
// Layout floors (derived): A[16r][8ch] f32, chunk' = ch ^ (r&7);
// B^T[col][32ch] bf16, chunk' = ch ^ (col&7) -> all b128 reads at the
// 8-cycle minimum; DMA dest is linear (source carries the inverse swizzle).

typedef __attribute__((ext_vector_type(8))) __bf16 bf16x8;
typedef __attribute__((ext_vector_type(4))) float f32x4;
typedef __attribute__((ext_vector_type(4))) unsigned int u32x4;
typedef __attribute__((ext_vector_type(2))) unsigned int u32x2;

#define BOFF 0        // B^T panel: 128 cols x 512B = 64KB
#define AOFF 65536    // A tiles: 4 waves x 2 bufs x 2KB = 16KB

__device__ __forceinline__ f32x4 MFMA(u32x4 a, u32x4 b, f32x4 c) {
    return __builtin_amdgcn_mfma_f32_16x16x32_bf16(
        __builtin_bit_cast(bf16x8, a), __builtin_bit_cast(bf16x8, b), c, 0, 0, 0);
}

__device__ __forceinline__ unsigned pk2(float a, float b) {
    __hip_bfloat16 ha = __float2bfloat16(a);
    __hip_bfloat16 hb = __float2bfloat16(b);
    unsigned short sa, sb;
    __builtin_memcpy(&sa, &ha, 2);
    __builtin_memcpy(&sb, &hb, 2);
    return (unsigned)sa | ((unsigned)sb << 16);
}

__global__ __launch_bounds__(256, 2) void argemm_kernel(
    const float* __restrict__ x,
    const int* __restrict__ idx,
    const float* __restrict__ w,
    const float* __restrict__ bias,
    float* __restrict__ out)
{
    __shared__ __align__(16) char lds[81920];

    const int tid = threadIdx.x;
    const int l   = tid & 63;
    const int wid = tid >> 6;        // 0..3: wave owns rows wid*16..+15
    const int g   = l >> 4;          // 0..3 (k-subgroup)
    const int i   = l & 15;          // 0..15
    const int ik  = i & 7;

    // XCD-chunked swizzle; logical bit0 = o-half (twin blocks adjacent ->
    // same XCD -> x L2 twin-hit), bits1-2 = n-tile, rest = b.
    const unsigned bid     = blockIdx.x;
    const unsigned chunk   = gridDim.x >> 3;
    const unsigned logical = (bid & 7u) * chunk + (bid >> 3);
    const int o0 = (int)(logical & 1u) * 128;
    const int n0 = (int)((logical >> 1) & 3u) * 64;
    const int b  = (int)(logical >> 3);

    const int c = idx[b];
    const float* xb = x + (size_t)b * (256 * 256);
    const float* wb = w + (size_t)c * (256 * 256);

    // ================= w prologue: 128 cols x 256 k -> bf16 B^T =================
    // thread: o-quad m4 = (tid&31)*4, k-subrow kq = tid>>5; pass p: k=p*32+kq*4+dk
    const int kq = tid >> 5;
    const int m4 = (tid & 31) * 4;
    f32x4 rw[2][4];
    auto issueW = [&](int p, int ss) {
#pragma unroll
        for (int dk = 0; dk < 4; ++dk)
            rw[ss][dk] = *(const f32x4*)(wb + (p * 32 + kq * 4 + dk) * 256 + o0 + m4);
    };
    auto flushW = [&](int p, int ss) {
#pragma unroll
        for (int j = 0; j < 4; ++j) {
            const int col = m4 + j;
            const int ch  = (p * 4 + (kq >> 1)) ^ (col & 7);
            u32x2 pr;
            pr.x = pk2(rw[ss][0][j], rw[ss][1][j]);
            pr.y = pk2(rw[ss][2][j], rw[ss][3][j]);
            *(u32x2*)((char*)lds + BOFF + col * 512 + ch * 16 + (kq & 1) * 8) = pr;
        }
    };

    issueW(0, 0);
    __builtin_amdgcn_sched_barrier(0);
    issueW(1, 1);
    __builtin_amdgcn_sched_barrier(0);
#pragma unroll
    for (int p = 0; p < 8; ++p) {
        flushW(p, p & 1);
        if (p < 6) {
            issueW(p + 2, p & 1);
            __builtin_amdgcn_sched_barrier(0);
        }
    }
    asm volatile("s_waitcnt lgkmcnt(0)" ::: "memory");
    __builtin_amdgcn_sched_barrier(0);
    __builtin_amdgcn_s_barrier();        // THE ONLY BARRIER IN THE KERNEL

    // ================= per-wave A-tile DMA (global_load_lds, f32) =================
    // tile = 16 rows x 32 k = 2KB; linear LDS slot s = q*64+l -> r=s>>3, c=s&7;
    // source pre-swizzled: global chunk = c ^ (r&7)  =>  read-side XOR works.
    const float* srcA[2];
#pragma unroll
    for (int q = 0; q < 2; ++q) {
        const int s = q * 64 + l;
        const int r = s >> 3;
        const int cc = s & 7;
        srcA[q] = xb + (n0 + wid * 16 + r) * 256 + ((cc ^ (r & 7)) * 4);
    }
    char* const aBufBase = (char*)lds + AOFF + wid * 4096;

    auto issueA = [&](int t, int buf) {
        char* d = aBufBase + buf * 2048;
#pragma unroll
        for (int q = 0; q < 2; ++q)
            __builtin_amdgcn_global_load_lds(
                (const __attribute__((address_space(1))) void*)(srcA[q] + t * 32),
                (__attribute__((address_space(3))) void*)(d + q * 1024), 16, 0, 0);
    };

    // fragment read addresses
    const int aR0 = i * 128 + (((g * 2 + 0) ^ ik) * 16);
    const int aR1 = i * 128 + (((g * 2 + 1) ^ ik) * 16);
    int bR[8];
#pragma unroll
    for (int n = 0; n < 8; ++n) {
        const int col = n * 16 + i;
        bR[n] = col * 512 + ((g ^ (col & 7)) * 16);   // + t*64 applied via ^?
    }
    // NOTE: chunk for k-step t is (t*4+g) ^ (col&7); t*4 only touches bits>=2,
    // (col&7) only bits 0..2 of the XOR key overlap bit2.. -> compute fully:
    // we fold it per-iteration below instead of precomputing partial XORs.

    f32x4 acc[8];
#pragma unroll
    for (int n = 0; n < 8; ++n)
        acc[n] = (f32x4){0.f, 0.f, 0.f, 0.f};

    issueA(0, 0);
    issueA(1, 1);

    // ================= barrier-free K-loop =================
#pragma unroll
    for (int t = 0; t < 8; ++t) {
        if (t < 7) asm volatile("s_waitcnt vmcnt(2)" ::: "memory");
        else       asm volatile("s_waitcnt vmcnt(0)" ::: "memory");
        __builtin_amdgcn_sched_barrier(0);

        const char* Ab = aBufBase + (t & 1) * 2048;
        const f32x4 lo = *(const f32x4*)(Ab + aR0);
        const f32x4 hi = *(const f32x4*)(Ab + aR1);
        u32x4 bq[8];
#pragma unroll
        for (int n = 0; n < 8; ++n) {
            const int col = n * 16 + i;
            bq[n] = *(const u32x4*)((const char*)lds + BOFF + col * 512
                                    + (((t * 4 + g) ^ (col & 7)) * 16));
        }
        asm volatile("s_waitcnt lgkmcnt(0)" ::: "memory");
        __builtin_amdgcn_sched_barrier(0);
        if (t < 6) {
            issueA(t + 2, t & 1);          // WAR-safe: reads of buf t&1 retired
            __builtin_amdgcn_sched_barrier(0);
        }

        u32x4 af;
        af.x = pk2(lo.x, lo.y);
        af.y = pk2(lo.z, lo.w);
        af.z = pk2(hi.x, hi.y);
        af.w = pk2(hi.z, hi.w);
#pragma unroll
        for (int n = 0; n < 8; ++n)
            acc[n] = MFMA(af, bq[n], acc[n]);
    }

    // ================= epilogue: bias + LeakyReLU(0.2), f32 store =================
    float biasf[8];
#pragma unroll
    for (int n = 0; n < 8; ++n)
        biasf[n] = bias[o0 + n * 16 + i];

    float* ob = out + (size_t)b * (256 * 256)
              + (size_t)(n0 + wid * 16 + g * 4) * 256 + o0 + i;
#pragma unroll
    for (int r = 0; r < 4; ++r)
#pragma unroll
        for (int n = 0; n < 8; ++n) {
            float v = acc[n][r] + biasf[n];
            v = (v >= 0.f) ? v : 0.2f * v;
            ob[r * 256 + n * 16] = v;
        }
}

extern "C" void kernel_launch(void* const* d_in, const int* in_sizes, int n_in,
                              void* d_out, int out_size, void* d_ws, size_t ws_size,
                              hipStream_t stream) {
    const float* x    = (const float*)d_in[0];
    const int*   idx  = (const int*)d_in[1];
    const float* w    = (const float*)d_in[2];
    const float* bias = (const float*)d_in[3];
    float*       out  = (float*)d_out;
    (void)d_ws; (void)ws_size; (void)n_in; (void)out_size;

    const int B = in_sizes[1];          // 2048
    dim3 grid((unsigned)(B * 8)), block(256);
    hipLaunchKernelGGL(argemm_kernel, grid, block, 0, stream, x, idx, w, bias, out);
}

// Round 9
// 248.497 us; speedup vs baseline: 1.4355x; 1.4355x over previous
//
#include <hip/hip_runtime.h>
#include <hip/hip_bf16.h>

// AdaptiveReLULayer: out[b,n,o] = leaky( sum_i x[b,n,i] * weight[idx[b],i,o] + bias[o], 0.2 )
// B=2048, N=256, IN=256, OUT=256, C=1024.  f32 I/O; bf16 MFMA, f32 accum.
//
// R11 vs R8 (295us) / R10 (356us, FAILED: 80M bank-conflict cycles + 2KB/wave
// in-flight starved the barrier-free loop):
// The only counters differing materially across the 294-307 family:
//   * SQ_LDS_BANK_CONFLICT: R7's bbyte layout = 0.0 measured; R8's swz = 25M
//     (~14% of kernel cycles at 256 CUs).  -> port bbyte into R8's structure.
//   * Cache policy never varied: x read once/block and out never re-read, yet
//     both allocate in L2/L3 (1.3GB rotating through 256MB L3, thrashing the
//     268MB w panel).  -> __builtin_nontemporal_load on x, _store on out.
// Everything else is R8 verbatim: A panel (64r x 256k bf16, 32KB) staged once
// in prologue via coalesced 1KB row reads; B (w) depth-2 reg-staged named
// sets (pipeline-held proof: VGPR ~120), double-buffered 2x16KB; one
// lgkm+barrier pair per K-round; LDS = 64KB exactly.
// B staging (R7's measured-zero shape): thread = (o-quad q=tid&63, p-octet
// oct=tid>>6); reads 8 full k-rows 1KB-coalesced; writes u32x4 at
// bbyte(q*4+j, oct*8).  Frag reads: u32x4 at bbyte(col, g*8).

#define K_DIM 256
#define O_DIM 256
#define BK 32

typedef __attribute__((ext_vector_type(8))) __bf16 bf16x8;
typedef __attribute__((ext_vector_type(4))) float f32x4;
typedef __attribute__((ext_vector_type(4))) unsigned int u32x4;
typedef __attribute__((ext_vector_type(2))) unsigned int u32x2;

__device__ __forceinline__ f32x4 MFMA(u32x4 a, u32x4 b, f32x4 c) {
    return __builtin_amdgcn_mfma_f32_16x16x32_bf16(
        __builtin_bit_cast(bf16x8, a), __builtin_bit_cast(bf16x8, b), c, 0, 0, 0);
}

__device__ __forceinline__ unsigned pk2(float a, float b) {
    __hip_bfloat16 ha = __float2bfloat16(a);
    __hip_bfloat16 hb = __float2bfloat16(b);
    unsigned short sa, sb;
    __builtin_memcpy(&sa, &ha, 2);
    __builtin_memcpy(&sb, &hb, 2);
    return (unsigned)sa | ((unsigned)sb << 16);
}

// B^T tile byte offset for (o 0..255, p 0..31): 128 row-pairs x 128B.
// Measured ZERO bank conflicts in R7 for both the u32x4 writes (o-quad/p-octet
// pattern) and the u32x4 frag reads (col = base+n*16+i, p = g*8).
__device__ __forceinline__ int bbyte(int o, int p) {
    const int rp  = o >> 1;
    const int raw = ((o & 1) << 2) | (p >> 3);
    const int key = (rp ^ (o >> 4)) & 7;
    return rp * 128 + ((raw ^ key) << 4) + ((p & 7) << 1);
}

__global__ __launch_bounds__(256) void argemm_kernel(
    const float* __restrict__ x,
    const int* __restrict__ idx,
    const float* __restrict__ w,
    const float* __restrict__ bias,
    float* __restrict__ out)
{
    __shared__ __align__(16) char lds[65536];  // A panel 32KB | B^T dbuf 2x16KB

    const int tid = threadIdx.x;
    const int l   = tid & 63;
    const int wid = tid >> 6;
    const int wr  = wid >> 1;   // 32-row half of the 64-row tile
    const int wc  = wid & 1;    // 128-col half of the 256-col tile

    // XCD-chunked swizzle: the 4 row-tiles of one b are logically adjacent ->
    // same XCD -> w[c] shared in that XCD's L2.
    const unsigned bid     = blockIdx.x;
    const unsigned chunk   = gridDim.x >> 3;
    const unsigned logical = (bid & 7u) * chunk + (bid >> 3);
    const int b  = (int)(logical >> 2);
    const int n0 = (int)(logical & 3u) * 64;

    const int g = l >> 4;   // 0..3 (k-subgroup)
    const int i = l & 15;   // 0..15

    const int c = idx[b];
    const float* xb = x + (size_t)b * (256 * 256);
    const float* wb = w + (size_t)c * (256 * 256);

    // ---- B staging maps (R7's measured-zero shape) ----
    const int q   = tid & 63;        // o-quad: cols q*4 .. q*4+3
    const int oct = tid >> 6;        // p-octet: p = oct*8 .. oct*8+7
    const float* wp = wb + (size_t)(oct * 8) * O_DIM + q * 4;
    int bW[4];
#pragma unroll
    for (int j = 0; j < 4; ++j)
        bW[j] = bbyte(q * 4 + j, oct * 8);

    // ---- fragment read addresses ----
    int bR[8];
#pragma unroll
    for (int n = 0; n < 8; ++n)
        bR[n] = bbyte(wc * 128 + n * 16 + i, g * 8);
    int aRow[2], aKey[2];
#pragma unroll
    for (int m = 0; m < 2; ++m) {
        const int r = wr * 32 + m * 16 + i;
        aRow[m] = r * 512;
        aKey[m] = r & 31;
    }

    // ---- two named B staging sets: tile T -> set T&1 ----
    f32x4 rb[2][8];   // [set][e]: k-row = T*32 + oct*8 + e

    auto issueB = [&](int t, int s) {
#pragma unroll
        for (int e = 0; e < 8; ++e)
            rb[s][e] = *(const f32x4*)(wp + (size_t)(t * BK + e) * O_DIM);
    };
    auto flushB = [&](int T, int s) {
        char* base = (char*)lds + 32768 + (T & 1) * 16384;
#pragma unroll
        for (int j = 0; j < 4; ++j) {
            u32x4 pq;                                   // 8 bf16, p ascending
            pq.x = pk2(rb[s][0][j], rb[s][1][j]);
            pq.y = pk2(rb[s][2][j], rb[s][3][j]);
            pq.z = pk2(rb[s][4][j], rb[s][5][j]);
            pq.w = pk2(rb[s][6][j], rb[s][7][j]);
            *(u32x4*)(base + bW[j]) = pq;
        }
    };

    // ---- prologue: B tiles 0,1 in flight; A panel staged (sequential, nt) ----
    issueB(0, 0);
    __builtin_amdgcn_sched_barrier(0);
    issueB(1, 1);
    __builtin_amdgcn_sched_barrier(0);

    // A: wave stages rows wid*16 .. wid*16+16; one full 1KB row per instr.
    {
        const float* xw = xb + (n0 + wid * 16) * 256 + l * 4;
        const int csw = l >> 1;            // k-chunk this lane holds
        const int sub = (l & 1) * 8;
        f32x4 xa[8];
#pragma unroll
        for (int s2 = 0; s2 < 2; ++s2) {
#pragma unroll
            for (int j = 0; j < 8; ++j)
                xa[j] = __builtin_nontemporal_load(
                    (const f32x4*)(xw + (s2 * 8 + j) * 256));
            __builtin_amdgcn_sched_barrier(0);
#pragma unroll
            for (int j = 0; j < 8; ++j) {
                const int r = wid * 16 + s2 * 8 + j;
                u32x2 p;
                p.x = pk2(xa[j].x, xa[j].y);
                p.y = pk2(xa[j].z, xa[j].w);
                *(u32x2*)((char*)lds + r * 512 + ((csw ^ (r & 31)) << 4) + sub) = p;
            }
        }
    }

    flushB(0, 0);
    issueB(2, 0);
    __builtin_amdgcn_sched_barrier(0);
    asm volatile("s_waitcnt lgkmcnt(0)" ::: "memory");
    __builtin_amdgcn_sched_barrier(0);
    __builtin_amdgcn_s_barrier();

    f32x4 acc[2][8];
#pragma unroll
    for (int m = 0; m < 2; ++m)
#pragma unroll
        for (int n = 0; n < 8; ++n)
            acc[m][n] = (f32x4){0.f, 0.f, 0.f, 0.f};

    // ---- K loop: 8 rounds; rounds touch only LDS (A) and L2/L3-resident w (B) ----
#pragma unroll
    for (int t = 0; t < 8; ++t) {
        const char* bbuf = (const char*)lds + 32768 + (t & 1) * 16384;

        u32x4 af[2];
#pragma unroll
        for (int m = 0; m < 2; ++m)
            af[m] = *(const u32x4*)((const char*)lds + aRow[m]
                                    + (((t * 4 + g) ^ aKey[m]) << 4));
#pragma unroll
        for (int n = 0; n < 8; ++n) {
            const u32x4 bq = *(const u32x4*)(bbuf + bR[n]);
#pragma unroll
            for (int m = 0; m < 2; ++m)
                acc[m][n] = MFMA(af[m], bq, acc[m][n]);
        }

        if (t < 7) {
            flushB(t + 1, (t + 1) & 1);   // loads issued 2 rounds ago
            if (t < 5) {
                issueB(t + 3, (t + 1) & 1);
                __builtin_amdgcn_sched_barrier(0);   // forbid load sinking (R5/R7 lesson)
            }
            asm volatile("s_waitcnt lgkmcnt(0)" ::: "memory");
            __builtin_amdgcn_sched_barrier(0);
            __builtin_amdgcn_s_barrier();
        }
    }

    // ---- epilogue: bias + LeakyReLU(0.2), nontemporal f32 store ----
    float biasf[8];
#pragma unroll
    for (int n = 0; n < 8; ++n)
        biasf[n] = bias[wc * 128 + n * 16 + i];

    float* ob = out + (size_t)b * (256 * 256);
#pragma unroll
    for (int m = 0; m < 2; ++m) {
#pragma unroll
        for (int r = 0; r < 4; ++r) {
            const int row = n0 + wr * 32 + m * 16 + g * 4 + r;
#pragma unroll
            for (int n = 0; n < 8; ++n) {
                float v = acc[m][n][r] + biasf[n];
                v = (v >= 0.f) ? v : 0.2f * v;
                __builtin_nontemporal_store(
                    v, &ob[row * 256 + wc * 128 + n * 16 + i]);
            }
        }
    }
}

extern "C" void kernel_launch(void* const* d_in, const int* in_sizes, int n_in,
                              void* d_out, int out_size, void* d_ws, size_t ws_size,
                              hipStream_t stream) {
    const float* x    = (const float*)d_in[0];
    const int*   idx  = (const int*)d_in[1];
    const float* w    = (const float*)d_in[2];
    const float* bias = (const float*)d_in[3];
    float*       out  = (float*)d_out;
    (void)d_ws; (void)ws_size; (void)n_in; (void)out_size;

    const int B = in_sizes[1];          // 2048
    dim3 grid((unsigned)(B * 4)), block(256);
    hipLaunchKernelGGL(argemm_kernel, grid, block, 0, stream, x, idx, w, bias, out);
}